// Round 2
// baseline (6337.457 us; speedup 1.0000x reference)
//
#include <hip/hip_runtime.h>
#include <hip/hip_bf16.h>

// Problem constants
#define B_    128
#define T_    512
#define IN_   128
#define H_    1024
#define OUT_  64
#define KTOT  1152          // IN_ + H_
#define GH    64            // hidden groups (16 units, 64 gate cols each)
#define GB    4             // batch groups (32 rows each)

typedef short bf16x8 __attribute__((ext_vector_type(8)));
typedef float f32x4  __attribute__((ext_vector_type(4)));
typedef unsigned short u16x2 __attribute__((ext_vector_type(2)));

#define MFMA(a,b,c) __builtin_amdgcn_mfma_f32_16x16x32_bf16((a),(b),(c),0,0,0)

__device__ __forceinline__ unsigned short f2bf(float x) {
    unsigned int xi = __float_as_uint(x);
    unsigned int r  = (xi + 0x7fffu + ((xi >> 16) & 1u)) >> 16;
    return (unsigned short)r;
}

// ---------------------------------------------------------------------------
// Pack combined recurrent weights: Wp[c][k] bf16, c = gh*64 + unit_local*4 + gate
// gate 0,1,2 = f,i,z (kernel_fiz col gate*H + j); gate 3 = r (kernel_r col j)
// ---------------------------------------------------------------------------
__global__ void pack_weights(const float* __restrict__ kfiz, const float* __restrict__ kr,
                             const float* __restrict__ bfiz, const float* __restrict__ br,
                             unsigned short* __restrict__ Wp, float* __restrict__ biasp)
{
    const int c    = blockIdx.x;            // 0..4095
    const int gh   = c >> 6, nl = c & 63;
    const int j    = gh * 16 + (nl >> 2);
    const int gate = nl & 3;
    for (int k = threadIdx.x; k < KTOT; k += 256) {
        float v = (gate < 3) ? kfiz[(size_t)k * 3072 + gate * 1024 + j]
                             : kr[(size_t)k * 1024 + j];
        Wp[(size_t)c * KTOT + k] = f2bf(v);
    }
    if (threadIdx.x == 0)
        biasp[c] = (gate < 3) ? bfiz[gate * 1024 + j] : br[j];
}

// u (B,T,IN) fp32 -> Ubf (T,B,IN) bf16
__global__ void pack_u(const float* __restrict__ u, unsigned short* __restrict__ Ubf)
{
    size_t i = (size_t)blockIdx.x * 256 + threadIdx.x;   // < 8388608
    int t = (int)(i >> 14);
    int rem = (int)(i & 16383);
    int b = rem >> 7, k = rem & 127;
    Ubf[i] = f2bf(u[((size_t)b << 16) + ((size_t)t << 7) + k]);
}

// W_out (H,OUT) fp32 -> Wob[o][k] bf16
__global__ void pack_wout(const float* __restrict__ wo, unsigned short* __restrict__ Wob)
{
    const int o = blockIdx.x;               // 0..63
    for (int k = threadIdx.x; k < H_; k += 256)
        Wob[(size_t)o * H_ + k] = f2bf(wo[(size_t)k * OUT_ + o]);
}

// ---------------------------------------------------------------------------
// Persistent recurrent scan, SENTINEL-SYNCED (flagless).
// Hall is pre-memset to 0xFF; 0xFFFF (bf16 -NaN) is unreachable as an h value
// (h = z*tanh(c) in (-1,1), h0 in [0,1); f2bf of any finite float != 0xFFFF),
// so consumers spin on their own data granules with agent-scope 8B loads and a
// packed-u16 max sentinel check. When the check passes, the polled registers
// ARE the MFMA A-operand (discovery and data-load merged into one LLC trip).
// Producers publish fire-and-forget: in-register 4x4 transpose (2x shfl_xor)
// -> one 8B agent store per row; no waitcnt drain, no flag, no wave0 funnel.
// Spin is capped (8192 + s_sleep backoff): a sync bug degrades to a visible
// absmax failure, never a hang/timeout.
// Barriers per step: B2a (__syncthreads, LDS partial exchange) + one raw
// s_barrier (asm, memory-clobbered so LDS ops can't be compiler-hoisted
// across it; no vmcnt drain so store acks stay off the critical path).
// ---------------------------------------------------------------------------
__global__ void __launch_bounds__(512, 2)
lstm_scan(const float* __restrict__ x0,
          const unsigned short* __restrict__ Wp,
          const float* __restrict__ biasp,
          const unsigned short* __restrict__ Ubf,
          unsigned short* __restrict__ Hall)
{
    __shared__ float part[4 * 8 * 320];       // [nj][mi*4+tl][col*20 + row] 40 KB

    const int tid  = threadIdx.x;
    const int bid  = blockIdx.x;
    const int gb   = (bid & 7) >> 1;                 // XCD-pair -> one gb group
    const int gh   = ((bid & 1) << 5) | (bid >> 3);  // 0..63, unique per gb
    const int wave = tid >> 6;
    const int lane = tid & 63;
    const int mi   = wave & 1;
    const int nj   = wave >> 1;               // K-slice AND owner-tile index, 0..3
    const int quad = lane >> 4;
    const int l15  = lane & 15;
    const int g    = l15 & 3;                 // gate id of this lane's column

    // Weights: tile tl cols gh*64+tl*16+l15, K-slice nj chunks kk (9 x 32).
    f32x4 wregf[36];
    #pragma unroll
    for (int tl = 0; tl < 4; ++tl)
        #pragma unroll
        for (int kk = 0; kk < 9; ++kk)
            wregf[tl * 9 + kk] = *reinterpret_cast<const f32x4*>(
                Wp + (size_t)(gh * 64 + tl * 16 + l15) * KTOT + nj * 288 + kk * 32 + quad * 8);
    #pragma unroll
    for (int i = 0; i < 36; ++i)
        asm volatile("" : "+v"(wregf[i]));    // pin: no remat, keep in VGPRs

    const float bias = biasp[gh * 64 + nj * 16 + l15];   // owner-role bias

    const int rowBase = gb * 32 + mi * 16;
    const int j       = gh * 16 + nj * 4 + (l15 >> 2);   // owner-role unit col

    // c-state (fp32, replicated across the 4 gate lanes of each unit)
    float cst[4];
    #pragma unroll
    for (int r = 0; r < 4; ++r)
        cst[r] = x0[(size_t)(rowBase + quad * 4 + r) * 2048 + 1024 + j];

    // h0 -> Hall[0] (fire-and-forget; consumers sentinel-poll it)
    {
        int m = tid >> 4, uu = tid & 15;      // 512 threads, 512 elems
        int b = gb * 32 + m, jj = gh * 16 + uu;
        unsigned short hv = f2bf(x0[(size_t)b * 2048 + jj]);
        __hip_atomic_store(&Hall[(size_t)b * H_ + jj], hv,
                           __ATOMIC_RELAXED, __HIP_MEMORY_SCOPE_AGENT);
    }

    const int aRow = rowBase + l15;            // A-frag row (batch index)
    const unsigned short* aU  = Ubf  + (size_t)aRow * IN_ + quad * 8;
    const unsigned short* aHb = Hall + (size_t)aRow * H_  + quad * 8 + nj * 288 - 128;

    const int kk0 = (nj == 0) ? 4 : 0;         // h-granule start (0..3 = u for nj0)

    for (int t = 0; t < T_; ++t) {
        f32x4 acc[4] = {{0.f,0.f,0.f,0.f},{0.f,0.f,0.f,0.f},
                        {0.f,0.f,0.f,0.f},{0.f,0.f,0.f,0.f}};

        // ---- u-part (nj==0 waves own K-chunks 0..3 = u): overlaps remote publish
        if (nj == 0) {
            const unsigned short* au = aU + (size_t)t * (B_ * IN_);
            #pragma unroll
            for (int kk = 0; kk < 4; ++kk) {
                bf16x8 av = *reinterpret_cast<const bf16x8*>(au + kk * 32);
                #pragma unroll
                for (int tl = 0; tl < 4; ++tl)
                    acc[tl] = MFMA(av, __builtin_bit_cast(bf16x8, wregf[tl * 9 + kk]), acc[tl]);
            }
        }

        // ---- sentinel poll + load of this wave's h slice (agent-scope 8B) ----
        union AU { unsigned long long q[2]; bf16x8 v; } A[9];
        const unsigned short* ah = aHb + (size_t)t * (B_ * H_);
        for (int spin = 0; spin < 8192; ++spin) {
            u16x2 mx = (u16x2){0, 0};
            #pragma unroll
            for (int kk = 0; kk < 9; ++kk)
                if (kk >= kk0) {
                    const unsigned long long* gp =
                        reinterpret_cast<const unsigned long long*>(ah + kk * 32);
                    A[kk].q[0] = __hip_atomic_load(gp,     __ATOMIC_RELAXED, __HIP_MEMORY_SCOPE_AGENT);
                    A[kk].q[1] = __hip_atomic_load(gp + 1, __ATOMIC_RELAXED, __HIP_MEMORY_SCOPE_AGENT);
                }
            #pragma unroll
            for (int kk = 0; kk < 9; ++kk)
                if (kk >= kk0) {
                    #pragma unroll
                    for (int hf = 0; hf < 2; ++hf) {
                        unsigned long long q = A[kk].q[hf];
                        mx = __builtin_elementwise_max(mx, __builtin_bit_cast(u16x2, (unsigned int)q));
                        mx = __builtin_elementwise_max(mx, __builtin_bit_cast(u16x2, (unsigned int)(q >> 32)));
                    }
                }
            bool ok = (mx.x != 0xFFFFu) && (mx.y != 0xFFFFu);
            if (__all(ok)) break;              // data valid -> it's already in regs
            __builtin_amdgcn_s_sleep(1);       // ~64 cy backoff: cut LLC poll storm
        }

        // ---- h-part MFMAs straight off the polled registers ----
        #pragma unroll
        for (int kk = 0; kk < 9; ++kk)
            if (kk >= kk0) {
                #pragma unroll
                for (int tl = 0; tl < 4; ++tl)
                    acc[tl] = MFMA(A[kk].v, __builtin_bit_cast(bf16x8, wregf[tl * 9 + kk]), acc[tl]);
            }

        // ---- write partials to LDS: part[nj][mi*4+tl][col l15][rows quad*4..] ----
        #pragma unroll
        for (int tl = 0; tl < 4; ++tl)
            *reinterpret_cast<f32x4*>(
                &part[(nj * 8 + mi * 4 + tl) * 320 + l15 * 20 + quad * 4]) = acc[tl];
        __syncthreads();                       // B2a: partials visible

        // ---- owner reduce (this wave owns tile tl == nj for row-half mi) ----
        f32x4 s = {bias, bias, bias, bias};
        {
            const int rbase = (mi * 4 + nj) * 320 + l15 * 20 + quad * 4;
            #pragma unroll
            for (int njj = 0; njj < 4; ++njj)
                s += *reinterpret_cast<const f32x4*>(&part[njj * 2560 + rbase]);
        }

        // ---- epilogue: activations, cross-gate exchange, state update ----
        unsigned int hx = 0, hy = 0;           // 4 packed bf16 hn (rows r=0..3)
        #pragma unroll
        for (int r = 0; r < 4; ++r) {
            float pre = s[r];
            float sg  = 1.0f / (1.0f + __expf((g == 3) ? -2.0f * pre : -pre));
            float act = (g == 3) ? 2.0f * sg - 1.0f : sg;
            float x1 = __shfl_xor(act, 1);
            float x2 = __shfl_xor(act, 2);
            float x3 = __shfl_xor(x1, 2);
            float fv = (g == 0) ? act : (g == 1) ? x1 : (g == 2) ? x2 : x3;
            int gi = g ^ 1;
            float iv = (gi == 0) ? act : (gi == 1) ? x1 : (gi == 2) ? x2 : x3;
            int gz = g ^ 2;
            float zv = (gz == 0) ? act : (gz == 1) ? x1 : (gz == 2) ? x2 : x3;
            int gr = g ^ 3;
            float rv = (gr == 0) ? act : (gr == 1) ? x1 : (gr == 2) ? x2 : x3;

            float cn = fv * cst[r] + iv * rv;
            cst[r] = cn;
            float th = 2.0f / (1.0f + __expf(-2.0f * cn)) - 1.0f;
            float hn = zv * th;
            unsigned int hb = f2bf(hn);
            if (r == 0)      hx  = hb;
            else if (r == 1) hx |= hb << 16;
            else if (r == 2) hy  = hb;
            else             hy |= hb << 16;
        }

        // ---- in-register 4x4 transpose among lanes differing in bits 2..3 ----
        // M[unit_local][r] -> lane u holds row quad*4+u, 4 units packed as
        // ushorts [u0,u1,u2,u3] (matches Hall row-major layout).
        unsigned int px = __shfl_xor((int)hx, 4), py = __shfl_xor((int)hy, 4);
        unsigned int ax, ay;
        if ((lane & 4) == 0) { ax = (hx & 0xFFFFu) | (px << 16);
                               ay = (hy & 0xFFFFu) | (py << 16); }
        else                 { ax = (px >> 16) | (hx & 0xFFFF0000u);
                               ay = (py >> 16) | (hy & 0xFFFF0000u); }
        unsigned int qx = __shfl_xor((int)ax, 8), qy = __shfl_xor((int)ay, 8);
        unsigned int bx, by;
        if ((lane & 8) == 0) { bx = ax; by = qx; }
        else                 { bx = qy; by = ay; }

        // ---- fire-and-forget publish: one 8B agent store per row, no drain ----
        if (g == 0) {
            int rr = mi * 16 + quad * 4 + (l15 >> 2);
            size_t base = (size_t)(t + 1) * (B_ * H_)
                        + (size_t)(gb * 32 + rr) * H_ + gh * 16 + nj * 4;
            unsigned long long val = ((unsigned long long)by << 32) | bx;
            __hip_atomic_store((unsigned long long*)&Hall[base], val,
                               __ATOMIC_RELAXED, __HIP_MEMORY_SCOPE_AGENT);
        }

        // raw barrier: no vmcnt drain (store acks off the critical path), but
        // memory-clobbered so the compiler can't hoist next-iter LDS writes
        // above it (HW DS ops are in-order per wave, so no lgkmcnt needed).
        asm volatile("s_barrier" ::: "memory");
    }
}

// ---------------------------------------------------------------------------
// y[b][t][o] = Hall[t+1][b][:] @ Wob[o][:] + bout[o]
// ---------------------------------------------------------------------------
__global__ void __launch_bounds__(256, 2)
out_gemm(const unsigned short* __restrict__ Hall,
         const unsigned short* __restrict__ Wob,
         const float* __restrict__ bout,
         float* __restrict__ y)
{
    const int tid  = threadIdx.x, wave = tid >> 6, lane = tid & 63;
    const int quad = lane >> 4, l15 = lane & 15;
    const int R    = blockIdx.x * 64 + wave * 16;      // flat row t*128+b

    f32x4 acc[4];
    #pragma unroll
    for (int nt = 0; nt < 4; ++nt) {
        float bb = bout[nt * 16 + l15];
        acc[nt] = {bb, bb, bb, bb};
    }
    const unsigned short* ap = Hall + (size_t)(R + l15 + B_) * H_ + quad * 8;
    #pragma unroll 4
    for (int kk = 0; kk < 32; ++kk) {
        bf16x8 av = *reinterpret_cast<const bf16x8*>(ap + kk * 32);
        #pragma unroll
        for (int nt = 0; nt < 4; ++nt) {
            bf16x8 bv = *reinterpret_cast<const bf16x8*>(
                Wob + (size_t)(nt * 16 + l15) * H_ + kk * 32 + quad * 8);
            acc[nt] = MFMA(av, bv, acc[nt]);
        }
    }
    #pragma unroll
    for (int nt = 0; nt < 4; ++nt)
        #pragma unroll
        for (int r = 0; r < 4; ++r) {
            int row = R + quad * 4 + r;
            int b = row & 127, t = row >> 7;
            y[((size_t)b << 15) + ((size_t)t << 6) + nt * 16 + l15] = acc[nt][r];
        }
}

// ---------------------------------------------------------------------------
extern "C" void kernel_launch(void* const* d_in, const int* in_sizes, int n_in,
                              void* d_out, int out_size, void* d_ws, size_t ws_size,
                              hipStream_t stream)
{
    const float* u    = (const float*)d_in[0];
    const float* x0   = (const float*)d_in[1];
    const float* kfiz = (const float*)d_in[2];
    const float* bfiz = (const float*)d_in[3];
    const float* kr   = (const float*)d_in[4];
    const float* br   = (const float*)d_in[5];
    const float* wo   = (const float*)d_in[6];
    const float* bo   = (const float*)d_in[7];
    float* y = (float*)d_out;

    char* ws = (char*)d_ws;
    size_t off = 0;
    unsigned short* Wp    = (unsigned short*)(ws + off); off += (size_t)4096 * KTOT * 2;        // 9,437,184
    float*          biasp = (float*)(ws + off);          off += (size_t)4096 * 4;               // 16,384
    unsigned short* Wob   = (unsigned short*)(ws + off); off += (size_t)OUT_ * H_ * 2;          // 131,072
    unsigned short* Ubf   = (unsigned short*)(ws + off); off += (size_t)T_ * B_ * IN_ * 2;      // 16,777,216
    unsigned short* Hall  = (unsigned short*)(ws + off); off += (size_t)(T_ + 1) * B_ * H_ * 2; // 134,479,872
    if (off > ws_size) return;   // workspace too small: deterministic visible failure

    // Sentinel-fill Hall: 0xFFFF bf16 (-NaN) is unreachable as an h value.
    hipMemsetAsync(Hall, 0xFF, (size_t)(T_ + 1) * B_ * H_ * 2, stream);
    hipLaunchKernelGGL(pack_weights, dim3(4096),  dim3(256), 0, stream, kfiz, kr, bfiz, br, Wp, biasp);
    hipLaunchKernelGGL(pack_u,       dim3(32768), dim3(256), 0, stream, u, Ubf);
    hipLaunchKernelGGL(pack_wout,    dim3(64),    dim3(256), 0, stream, wo, Wob);

    void* args[] = { (void*)&x0, (void*)&Wp, (void*)&biasp, (void*)&Ubf, (void*)&Hall };
    hipLaunchCooperativeKernel((void*)lstm_scan, dim3(GB * GH), dim3(512), args, 0, stream);

    hipLaunchKernelGGL(out_gemm, dim3((T_ * B_) / 64), dim3(256), 0, stream, Hall, Wob, bo, y);
}

// Round 3
// 3104.274 us; speedup vs baseline: 2.0415x; 2.0415x over previous
//
#include <hip/hip_runtime.h>
#include <hip/hip_bf16.h>

// Problem constants
#define B_    128
#define T_    512
#define IN_   128
#define H_    1024
#define OUT_  64
#define KTOT  1152          // IN_ + H_
#define GH    64            // hidden groups (16 units, 64 gate cols each)
#define GB    4             // batch groups (32 rows each)

typedef short bf16x8 __attribute__((ext_vector_type(8)));
typedef float f32x4  __attribute__((ext_vector_type(4)));

#define MFMA(a,b,c) __builtin_amdgcn_mfma_f32_16x16x32_bf16((a),(b),(c),0,0,0)

__device__ __forceinline__ unsigned short f2bf(float x) {
    unsigned int xi = __float_as_uint(x);
    unsigned int r  = (xi + 0x7fffu + ((xi >> 16) & 1u)) >> 16;
    return (unsigned short)r;
}

// ---------------------------------------------------------------------------
// Pack combined recurrent weights: Wp[c][k] bf16, c = gh*64 + unit_local*4 + gate
// gate 0,1,2 = f,i,z (kernel_fiz col gate*H + j); gate 3 = r (kernel_r col j)
// ---------------------------------------------------------------------------
__global__ void pack_weights(const float* __restrict__ kfiz, const float* __restrict__ kr,
                             const float* __restrict__ bfiz, const float* __restrict__ br,
                             unsigned short* __restrict__ Wp, float* __restrict__ biasp)
{
    const int c    = blockIdx.x;            // 0..4095
    const int gh   = c >> 6, nl = c & 63;
    const int j    = gh * 16 + (nl >> 2);
    const int gate = nl & 3;
    for (int k = threadIdx.x; k < KTOT; k += 256) {
        float v = (gate < 3) ? kfiz[(size_t)k * 3072 + gate * 1024 + j]
                             : kr[(size_t)k * 1024 + j];
        Wp[(size_t)c * KTOT + k] = f2bf(v);
    }
    if (threadIdx.x == 0)
        biasp[c] = (gate < 3) ? bfiz[gate * 1024 + j] : br[j];
}

// u (B,T,IN) fp32 -> Ubf (T,B,IN) bf16
__global__ void pack_u(const float* __restrict__ u, unsigned short* __restrict__ Ubf)
{
    size_t i = (size_t)blockIdx.x * 256 + threadIdx.x;   // < 8388608
    int t = (int)(i >> 14);
    int rem = (int)(i & 16383);
    int b = rem >> 7, k = rem & 127;
    Ubf[i] = f2bf(u[((size_t)b << 16) + ((size_t)t << 7) + k]);
}

// W_out (H,OUT) fp32 -> Wob[o][k] bf16
__global__ void pack_wout(const float* __restrict__ wo, unsigned short* __restrict__ Wob)
{
    const int o = blockIdx.x;               // 0..63
    for (int k = threadIdx.x; k < H_; k += 256)
        Wob[(size_t)o * H_ + k] = f2bf(wo[(size_t)k * OUT_ + o]);
}

// ---------------------------------------------------------------------------
// Persistent recurrent scan, FLAG-SYNCED v2.
// vs round-0 baseline (proven 2620us):
//  * Distributed publish: each wave transposes its 16x4 hn tile in-register
//    (2x shfl_xor butterfly) and stores it directly (16 x 8B agent stores);
//    per-wave s_waitcnt vmcnt(0) drain runs in PARALLEL across waves, then a
//    raw s_barrier, then tid0 sets the per-WG flag. Deletes hT LDS staging,
//    barrier B2b, and the wave0 LDS re-read from the producer tail.
//  * Subset polling: wave (mi,nj) polls only its 18 (10 for nj=0) producer
//    flags (cols [18nj-8,18nj+10)) and proceeds straight to its h-loads;
//    barrier B1 deleted. Slow-producer wait overlaps fast waves' load+MFMA.
//  * h data loads stay PLAIN (cached): 32 WGs/XCD share one gb -> the per-step
//    h-panel is fetched from LLC once and L2-amortized 32x (round-2 lesson:
//    agent-scope data polling forfeits this and congests the LLC).
// ---------------------------------------------------------------------------
__global__ void __launch_bounds__(512, 2)
lstm_scan(const float* __restrict__ x0,
          const unsigned short* __restrict__ Wp,
          const float* __restrict__ biasp,
          const unsigned short* __restrict__ Ubf,
          unsigned short* __restrict__ Hall,
          int* __restrict__ Flag)
{
    __shared__ float part[4 * 8 * 320];       // [nj][mi*4+tl][col*20 + row] 40 KB

    const int tid  = threadIdx.x;
    const int bid  = blockIdx.x;
    const int gb   = (bid & 7) >> 1;                 // XCD-pair -> one gb group
    const int gh   = ((bid & 1) << 5) | (bid >> 3);  // 0..63, unique per gb
    const int wave = tid >> 6;
    const int lane = tid & 63;
    const int mi   = wave & 1;
    const int nj   = wave >> 1;               // K-slice AND owner-tile index, 0..3
    const int quad = lane >> 4;
    const int l15  = lane & 15;
    const int g    = l15 & 3;                 // gate id of this lane's column

    // Weights: tile tl cols gh*64+tl*16+l15, K-slice nj chunks kk (9 x 32).
    f32x4 wregf[36];
    #pragma unroll
    for (int tl = 0; tl < 4; ++tl)
        #pragma unroll
        for (int kk = 0; kk < 9; ++kk)
            wregf[tl * 9 + kk] = *reinterpret_cast<const f32x4*>(
                Wp + (size_t)(gh * 64 + tl * 16 + l15) * KTOT + nj * 288 + kk * 32 + quad * 8);
    #pragma unroll
    for (int i = 0; i < 36; ++i)
        asm volatile("" : "+v"(wregf[i]));    // pin: no remat, keep in VGPRs

    const float bias = biasp[gh * 64 + nj * 16 + l15];   // owner-role bias

    const int rowBase = gb * 32 + mi * 16;
    const int j       = gh * 16 + nj * 4 + (l15 >> 2);   // owner-role unit col

    // c-state (fp32, replicated across the 4 gate lanes of each unit)
    float cst[4];
    #pragma unroll
    for (int r = 0; r < 4; ++r)
        cst[r] = x0[(size_t)(rowBase + quad * 4 + r) * 2048 + 1024 + j];

    // h0 -> Hall[0] (write-through; one-time). __syncthreads drains all waves'
    // stores (compiler emits vmcnt(0) before s_barrier), then tid0 sets flag 0.
    {
        int m = tid >> 4, uu = tid & 15;      // 512 threads, 512 elems
        int b = gb * 32 + m, jj = gh * 16 + uu;
        unsigned short hv = f2bf(x0[(size_t)b * 2048 + jj]);
        __hip_atomic_store(&Hall[(size_t)b * H_ + jj], hv,
                           __ATOMIC_RELAXED, __HIP_MEMORY_SCOPE_AGENT);
    }
    __syncthreads();
    if (tid == 0)
        __hip_atomic_store(&Flag[(size_t)gb * 64 + gh], 1,
                           __ATOMIC_RELAXED, __HIP_MEMORY_SCOPE_AGENT);

    const int aRow = rowBase + l15;            // A-frag row (batch index)
    const unsigned short* aU  = Ubf  + (size_t)aRow * IN_ + quad * 8;
    const unsigned short* aHb = Hall + (size_t)aRow * H_  + quad * 8;

    const int kk0 = (nj == 0) ? 4 : 0;         // post-poll chunk start

    // Subset-poll lane mapping: this wave depends on producer cols
    // [nj*288-128, nj*288+160) (for nj>=1) -> gh' in [18nj-8, 18nj+10).
    const int fBase = (nj == 0) ? 0 : (nj * 18 - 8);
    const int fCnt  = (nj == 0) ? 10 : 18;
    const int fl    = fBase + ((lane < fCnt) ? lane : (fCnt - 1));

    for (int t = 0; t < T_; ++t) {
        f32x4 acc[4] = {{0.f,0.f,0.f,0.f},{0.f,0.f,0.f,0.f},
                        {0.f,0.f,0.f,0.f},{0.f,0.f,0.f,0.f}};

        // ---- pre-poll u-part (nj==0 waves own K-chunks 0..3 = u) ----
        if (nj == 0) {
            const unsigned short* au = aU + (size_t)t * (B_ * IN_);
            #pragma unroll
            for (int kk = 0; kk < 4; ++kk) {
                bf16x8 av = *reinterpret_cast<const bf16x8*>(au + kk * 32);
                #pragma unroll
                for (int tl = 0; tl < 4; ++tl)
                    acc[tl] = MFMA(av, __builtin_bit_cast(bf16x8, wregf[tl * 9 + kk]), acc[tl]);
            }
        }

        // ---- per-wave subset flag poll (no WG barrier) ----
        {
            const int* fp = Flag + ((size_t)t * GB + gb) * 64 + fl;
            int v = __hip_atomic_load(fp, __ATOMIC_RELAXED, __HIP_MEMORY_SCOPE_AGENT);
            while (!__all(v != 0))
                v = __hip_atomic_load(fp, __ATOMIC_RELAXED, __HIP_MEMORY_SCOPE_AGENT);
        }

        // ---- h-part: this wave's K-slice (disjoint, L2-amortized plain loads)
        const unsigned short* ah = aHb + (size_t)t * (B_ * H_);
        bf16x8 a[9];
        #pragma unroll
        for (int kk = 0; kk < 9; ++kk)
            if (kk >= kk0)
                a[kk] = *reinterpret_cast<const bf16x8*>(ah + (nj * 288 - 128 + kk * 32));
        #pragma unroll
        for (int kk = 0; kk < 9; ++kk)
            if (kk >= kk0) {
                #pragma unroll
                for (int tl = 0; tl < 4; ++tl)
                    acc[tl] = MFMA(a[kk], __builtin_bit_cast(bf16x8, wregf[tl * 9 + kk]), acc[tl]);
            }

        // ---- write partials to LDS: part[nj][mi*4+tl][col l15][rows quad*4..] ----
        #pragma unroll
        for (int tl = 0; tl < 4; ++tl)
            *reinterpret_cast<f32x4*>(
                &part[(nj * 8 + mi * 4 + tl) * 320 + l15 * 20 + quad * 4]) = acc[tl];
        __syncthreads();                       // B2a: partials visible

        // ---- owner reduce (this wave owns tile tl == nj for row-half mi) ----
        f32x4 s = {bias, bias, bias, bias};
        {
            const int rbase = (mi * 4 + nj) * 320 + l15 * 20 + quad * 4;
            #pragma unroll
            for (int njj = 0; njj < 4; ++njj)
                s += *reinterpret_cast<const f32x4*>(&part[njj * 2560 + rbase]);
        }

        // ---- epilogue: activations, cross-gate exchange, state update ----
        unsigned int hx = 0, hy = 0;           // 4 packed bf16 hn (rows r=0..3)
        #pragma unroll
        for (int r = 0; r < 4; ++r) {
            float pre = s[r];
            float sg  = 1.0f / (1.0f + __expf((g == 3) ? -2.0f * pre : -pre));
            float act = (g == 3) ? 2.0f * sg - 1.0f : sg;
            float x1 = __shfl_xor(act, 1);
            float x2 = __shfl_xor(act, 2);
            float x3 = __shfl_xor(x1, 2);
            float fv = (g == 0) ? act : (g == 1) ? x1 : (g == 2) ? x2 : x3;
            int gi = g ^ 1;
            float iv = (gi == 0) ? act : (gi == 1) ? x1 : (gi == 2) ? x2 : x3;
            int gz = g ^ 2;
            float zv = (gz == 0) ? act : (gz == 1) ? x1 : (gz == 2) ? x2 : x3;
            int gr = g ^ 3;
            float rv = (gr == 0) ? act : (gr == 1) ? x1 : (gr == 2) ? x2 : x3;

            float cn = fv * cst[r] + iv * rv;
            cst[r] = cn;
            float th = 2.0f / (1.0f + __expf(-2.0f * cn)) - 1.0f;
            float hn = zv * th;
            unsigned int hb = f2bf(hn);
            if (r == 0)      hx  = hb;
            else if (r == 1) hx |= hb << 16;
            else if (r == 2) hy  = hb;
            else             hy |= hb << 16;
        }

        // ---- in-register 4x4 transpose among lanes differing in bits 2..3 ----
        // lane u of each 16-lane group ends up holding row quad*4+u's 4 units
        // packed as ushorts [u0,u1,u2,u3] (matches Hall row-major layout).
        unsigned int px = __shfl_xor((int)hx, 4), py = __shfl_xor((int)hy, 4);
        unsigned int ax, ay;
        if ((lane & 4) == 0) { ax = (hx & 0xFFFFu) | (px << 16);
                               ay = (hy & 0xFFFFu) | (py << 16); }
        else                 { ax = (px >> 16) | (hx & 0xFFFF0000u);
                               ay = (py >> 16) | (hy & 0xFFFF0000u); }
        unsigned int qx = __shfl_xor((int)ax, 8), qy = __shfl_xor((int)ay, 8);
        unsigned int bx, by;
        if ((lane & 8) == 0) { bx = ax; by = qx; }
        else                 { bx = qy; by = ay; }

        // ---- distributed publish: each wave stores its own 16x4 tile ----
        if (g == 0) {
            int rr = mi * 16 + quad * 4 + (l15 >> 2);
            size_t base = (size_t)(t + 1) * (B_ * H_)
                        + (size_t)(gb * 32 + rr) * H_ + gh * 16 + nj * 4;
            unsigned long long val = ((unsigned long long)by << 32) | bx;
            __hip_atomic_store((unsigned long long*)&Hall[base], val,
                               __ATOMIC_RELAXED, __HIP_MEMORY_SCOPE_AGENT);
        }

        // per-wave drain (parallel across the 8 waves), then raw barrier
        // (no redundant second drain), then the per-WG flag.
        asm volatile("s_waitcnt vmcnt(0)" ::: "memory");
        asm volatile("s_barrier" ::: "memory");
        if (tid == 0)
            __hip_atomic_store(&Flag[((size_t)(t + 1) * GB + gb) * 64 + gh], 1,
                               __ATOMIC_RELAXED, __HIP_MEMORY_SCOPE_AGENT);
    }
}

// ---------------------------------------------------------------------------
// y[b][t][o] = Hall[t+1][b][:] @ Wob[o][:] + bout[o]
// ---------------------------------------------------------------------------
__global__ void __launch_bounds__(256, 2)
out_gemm(const unsigned short* __restrict__ Hall,
         const unsigned short* __restrict__ Wob,
         const float* __restrict__ bout,
         float* __restrict__ y)
{
    const int tid  = threadIdx.x, wave = tid >> 6, lane = tid & 63;
    const int quad = lane >> 4, l15 = lane & 15;
    const int R    = blockIdx.x * 64 + wave * 16;      // flat row t*128+b

    f32x4 acc[4];
    #pragma unroll
    for (int nt = 0; nt < 4; ++nt) {
        float bb = bout[nt * 16 + l15];
        acc[nt] = {bb, bb, bb, bb};
    }
    const unsigned short* ap = Hall + (size_t)(R + l15 + B_) * H_ + quad * 8;
    #pragma unroll 4
    for (int kk = 0; kk < 32; ++kk) {
        bf16x8 av = *reinterpret_cast<const bf16x8*>(ap + kk * 32);
        #pragma unroll
        for (int nt = 0; nt < 4; ++nt) {
            bf16x8 bv = *reinterpret_cast<const bf16x8*>(
                Wob + (size_t)(nt * 16 + l15) * H_ + kk * 32 + quad * 8);
            acc[nt] = MFMA(av, bv, acc[nt]);
        }
    }
    #pragma unroll
    for (int nt = 0; nt < 4; ++nt)
        #pragma unroll
        for (int r = 0; r < 4; ++r) {
            int row = R + quad * 4 + r;
            int b = row & 127, t = row >> 7;
            y[((size_t)b << 15) + ((size_t)t << 6) + nt * 16 + l15] = acc[nt][r];
        }
}

// ---------------------------------------------------------------------------
extern "C" void kernel_launch(void* const* d_in, const int* in_sizes, int n_in,
                              void* d_out, int out_size, void* d_ws, size_t ws_size,
                              hipStream_t stream)
{
    const float* u    = (const float*)d_in[0];
    const float* x0   = (const float*)d_in[1];
    const float* kfiz = (const float*)d_in[2];
    const float* bfiz = (const float*)d_in[3];
    const float* kr   = (const float*)d_in[4];
    const float* br   = (const float*)d_in[5];
    const float* wo   = (const float*)d_in[6];
    const float* bo   = (const float*)d_in[7];
    float* y = (float*)d_out;

    char* ws = (char*)d_ws;
    size_t off = 0;
    unsigned short* Wp    = (unsigned short*)(ws + off); off += (size_t)4096 * KTOT * 2;        // 9,437,184
    float*          biasp = (float*)(ws + off);          off += (size_t)4096 * 4;               // 16,384
    unsigned short* Wob   = (unsigned short*)(ws + off); off += (size_t)OUT_ * H_ * 2;          // 131,072
    unsigned short* Ubf   = (unsigned short*)(ws + off); off += (size_t)T_ * B_ * IN_ * 2;      // 16,777,216
    unsigned short* Hall  = (unsigned short*)(ws + off); off += (size_t)(T_ + 1) * B_ * H_ * 2; // 134,479,872
    int*            Flag  = (int*)(ws + off);            off += (size_t)(T_ + 1) * GB * 64 * 4; // 525,312
    if (off > ws_size) return;   // workspace too small: deterministic visible failure

    hipMemsetAsync(Flag, 0, (size_t)(T_ + 1) * GB * 64 * 4, stream);
    hipLaunchKernelGGL(pack_weights, dim3(4096),  dim3(256), 0, stream, kfiz, kr, bfiz, br, Wp, biasp);
    hipLaunchKernelGGL(pack_u,       dim3(32768), dim3(256), 0, stream, u, Ubf);
    hipLaunchKernelGGL(pack_wout,    dim3(64),    dim3(256), 0, stream, wo, Wob);

    void* args[] = { (void*)&x0, (void*)&Wp, (void*)&biasp, (void*)&Ubf, (void*)&Hall, (void*)&Flag };
    hipLaunchCooperativeKernel((void*)lstm_scan, dim3(GB * GH), dim3(512), args, 0, stream);

    hipLaunchKernelGGL(out_gemm, dim3((T_ * B_) / 64), dim3(256), 0, stream, Hall, Wob, bo, y);
}

// Round 4
// 2060.624 us; speedup vs baseline: 3.0755x; 1.5065x over previous
//
#include <hip/hip_runtime.h>
#include <hip/hip_bf16.h>

// Problem constants
#define B_    128
#define T_    512
#define IN_   128
#define H_    1024
#define OUT_  64
#define KTOT  1152          // IN_ + H_
#define GH    64            // hidden groups (16 units, 64 gate cols each)
#define GB    4             // batch groups (32 rows each)
// Blocked Hall layout: [t][gh(64)][b(128)][16] ushort.
// t-slab stride = 131072 ushorts (256KB); gh block = 2048 ushorts (4KB).
#define HSLAB 131072
#define HBLK  2048

typedef short bf16x8 __attribute__((ext_vector_type(8)));
typedef float f32x4  __attribute__((ext_vector_type(4)));

#define MFMA(a,b,c) __builtin_amdgcn_mfma_f32_16x16x32_bf16((a),(b),(c),0,0,0)

__device__ __forceinline__ unsigned short f2bf(float x) {
    unsigned int xi = __float_as_uint(x);
    unsigned int r  = (xi + 0x7fffu + ((xi >> 16) & 1u)) >> 16;
    return (unsigned short)r;
}

// ---------------------------------------------------------------------------
// Pack combined recurrent weights: Wp[c][k] bf16, c = gh*64 + unit_local*4 + gate
// gate 0,1,2 = f,i,z (kernel_fiz col gate*H + j); gate 3 = r (kernel_r col j)
// ---------------------------------------------------------------------------
__global__ void pack_weights(const float* __restrict__ kfiz, const float* __restrict__ kr,
                             const float* __restrict__ bfiz, const float* __restrict__ br,
                             unsigned short* __restrict__ Wp, float* __restrict__ biasp)
{
    const int c    = blockIdx.x;            // 0..4095
    const int gh   = c >> 6, nl = c & 63;
    const int j    = gh * 16 + (nl >> 2);
    const int gate = nl & 3;
    for (int k = threadIdx.x; k < KTOT; k += 256) {
        float v = (gate < 3) ? kfiz[(size_t)k * 3072 + gate * 1024 + j]
                             : kr[(size_t)k * 1024 + j];
        Wp[(size_t)c * KTOT + k] = f2bf(v);
    }
    if (threadIdx.x == 0)
        biasp[c] = (gate < 3) ? bfiz[gate * 1024 + j] : br[j];
}

// u (B,T,IN) fp32 -> Ubf (T,B,IN) bf16
__global__ void pack_u(const float* __restrict__ u, unsigned short* __restrict__ Ubf)
{
    size_t i = (size_t)blockIdx.x * 256 + threadIdx.x;   // < 8388608
    int t = (int)(i >> 14);
    int rem = (int)(i & 16383);
    int b = rem >> 7, k = rem & 127;
    Ubf[i] = f2bf(u[((size_t)b << 16) + ((size_t)t << 7) + k]);
}

// W_out (H,OUT) fp32 -> Wob[o][k] bf16
__global__ void pack_wout(const float* __restrict__ wo, unsigned short* __restrict__ Wob)
{
    const int o = blockIdx.x;               // 0..63
    for (int k = threadIdx.x; k < H_; k += 256)
        Wob[(size_t)o * H_ + k] = f2bf(wo[(size_t)k * OUT_ + o]);
}

// ---------------------------------------------------------------------------
// Persistent recurrent scan — round-0 proven structure + BLOCKED Hall layout.
// Hall[t][gh][b][16]: each WG's per-step publish patch is 1KB CONTIGUOUS, so
// the wave0 funnel emits two fully-contiguous 512B store instructions (16
// complete 64B lines, single writer per line, no partial-line RMW at LLC);
// consumer A-loads become 2x contiguous 512B runs per instruction. Everything
// else (B1 poll, K-split waves, LDS partial reduce, hT staging, B2a/B2b,
// wave0 funnel + drain + per-WG flag) is identical to the 2620us baseline.
// ---------------------------------------------------------------------------
__global__ void __launch_bounds__(512, 2)
lstm_scan(const float* __restrict__ x0,
          const unsigned short* __restrict__ Wp,
          const float* __restrict__ biasp,
          const unsigned short* __restrict__ Ubf,
          unsigned short* __restrict__ Hall,
          int* __restrict__ Flag)
{
    __shared__ float part[4 * 8 * 320];       // [nj][mi*4+tl][col*20 + row] 40 KB
    __shared__ unsigned short hT[32 * 16];    // 1 KB h-tile for coalesced publish

    const int tid  = threadIdx.x;
    const int bid  = blockIdx.x;
    const int gb   = (bid & 7) >> 1;                 // XCD-pair -> one gb group
    const int gh   = ((bid & 1) << 5) | (bid >> 3);  // 0..63, unique per gb
    const int wave = tid >> 6;
    const int lane = tid & 63;
    const int mi   = wave & 1;
    const int nj   = wave >> 1;               // K-slice AND owner-tile index, 0..3
    const int quad = lane >> 4;
    const int l15  = lane & 15;
    const int g    = l15 & 3;                 // gate id of this lane's column

    // Weights: tile tl cols gh*64+tl*16+l15, K-slice nj chunks kk (9 x 32).
    f32x4 wregf[36];
    #pragma unroll
    for (int tl = 0; tl < 4; ++tl)
        #pragma unroll
        for (int kk = 0; kk < 9; ++kk)
            wregf[tl * 9 + kk] = *reinterpret_cast<const f32x4*>(
                Wp + (size_t)(gh * 64 + tl * 16 + l15) * KTOT + nj * 288 + kk * 32 + quad * 8);
    #pragma unroll
    for (int i = 0; i < 36; ++i)
        asm volatile("" : "+v"(wregf[i]));    // pin: no remat, keep in VGPRs

    const float bias = biasp[gh * 64 + nj * 16 + l15];   // owner-role bias

    const int rowBase = gb * 32 + mi * 16;
    const int j       = gh * 16 + nj * 4 + (l15 >> 2);   // owner-role unit col

    // c-state (fp32, replicated across the 4 gate lanes of each unit)
    float cst[4];
    #pragma unroll
    for (int r = 0; r < 4; ++r)
        cst[r] = x0[(size_t)(rowBase + quad * 4 + r) * 2048 + 1024 + j];

    // h0 -> Hall[0] (blocked layout; 512 threads write the WG's 1KB patch of
    // block gh, rows gb*32..+32 -> fully contiguous, coalesced full lines)
    {
        int m = tid >> 4, uu = tid & 15;      // 512 threads, 512 elems
        int b = gb * 32 + m;
        unsigned short hv = f2bf(x0[(size_t)b * 2048 + gh * 16 + uu]);
        __hip_atomic_store(&Hall[(size_t)gh * HBLK + (size_t)b * 16 + uu], hv,
                           __ATOMIC_RELAXED, __HIP_MEMORY_SCOPE_AGENT);
    }
    __syncthreads();                           // vmcnt(0) drain per wave
    if (tid == 0)
        __hip_atomic_store(&Flag[(size_t)gb * 64 + gh], 1,
                           __ATOMIC_RELAXED, __HIP_MEMORY_SCOPE_AGENT);

    const int aRow = rowBase + l15;            // A-frag row (batch index)
    const unsigned short* aU = Ubf + (size_t)aRow * IN_ + quad * 8;
    // Blocked consumer base: lane-const part. Chunk kk (col c = nj*288-128+kk*32)
    // lives in block (nj*18-8+2*kk)+(quad>>1), byte-col (quad&1)*8 ushorts.
    const unsigned short* aH = Hall + (size_t)aRow * 16 + (quad >> 1) * HBLK + (quad & 1) * 8;
    const ptrdiff_t hBlk0 = (ptrdiff_t)(nj * 18 - 8) * HBLK;   // kk=0 block offset

    const int kk0 = (nj == 0) ? 4 : 0;         // post-poll chunk start

    for (int t = 0; t < T_; ++t) {
        f32x4 acc[4] = {{0.f,0.f,0.f,0.f},{0.f,0.f,0.f,0.f},
                        {0.f,0.f,0.f,0.f},{0.f,0.f,0.f,0.f}};

        // ---- pre-poll u-part (nj==0 waves own K-chunks 0..3 = u) ----
        if (nj == 0) {
            const unsigned short* au = aU + (size_t)t * (B_ * IN_);
            #pragma unroll
            for (int kk = 0; kk < 4; ++kk) {
                bf16x8 av = *reinterpret_cast<const bf16x8*>(au + kk * 32);
                #pragma unroll
                for (int tl = 0; tl < 4; ++tl)
                    acc[tl] = MFMA(av, __builtin_bit_cast(bf16x8, wregf[tl * 9 + kk]), acc[tl]);
            }
        }

        // ---- wait for h[t]: 64-lane parallel flag poll (reads only) ----
        if (wave == 0) {
            const int* fp = Flag + ((size_t)t * GB + gb) * 64 + lane;
            int v = __hip_atomic_load(fp, __ATOMIC_RELAXED, __HIP_MEMORY_SCOPE_AGENT);
            while (!__all(v != 0))
                v = __hip_atomic_load(fp, __ATOMIC_RELAXED, __HIP_MEMORY_SCOPE_AGENT);
        }
        __syncthreads();                       // B1

        // ---- h-part: this wave's K-slice (blocked layout, 512B-run loads) ----
        const ptrdiff_t hoff = (ptrdiff_t)t * HSLAB + hBlk0;
        bf16x8 a[9];
        #pragma unroll
        for (int kk = 0; kk < 9; ++kk)
            if (kk >= kk0)
                a[kk] = *reinterpret_cast<const bf16x8*>(aH + hoff + (ptrdiff_t)kk * (2 * HBLK));
        #pragma unroll
        for (int kk = 0; kk < 9; ++kk)
            if (kk >= kk0) {
                #pragma unroll
                for (int tl = 0; tl < 4; ++tl)
                    acc[tl] = MFMA(a[kk], __builtin_bit_cast(bf16x8, wregf[tl * 9 + kk]), acc[tl]);
            }

        // ---- write partials to LDS: part[nj][mi*4+tl][col l15][rows quad*4..] ----
        #pragma unroll
        for (int tl = 0; tl < 4; ++tl)
            *reinterpret_cast<f32x4*>(
                &part[(nj * 8 + mi * 4 + tl) * 320 + l15 * 20 + quad * 4]) = acc[tl];
        __syncthreads();                       // B2a

        // ---- owner reduce (this wave owns tile tl == nj for row-half mi) ----
        f32x4 s = {bias, bias, bias, bias};
        {
            const int rbase = (mi * 4 + nj) * 320 + l15 * 20 + quad * 4;
            #pragma unroll
            for (int njj = 0; njj < 4; ++njj)
                s += *reinterpret_cast<const f32x4*>(&part[njj * 2560 + rbase]);
        }

        // ---- epilogue: activations, cross-gate exchange, state update ----
        #pragma unroll
        for (int r = 0; r < 4; ++r) {
            float pre = s[r];
            float sg  = 1.0f / (1.0f + __expf((g == 3) ? -2.0f * pre : -pre));
            float act = (g == 3) ? 2.0f * sg - 1.0f : sg;
            float x1 = __shfl_xor(act, 1);
            float x2 = __shfl_xor(act, 2);
            float x3 = __shfl_xor(x1, 2);
            float fv = (g == 0) ? act : (g == 1) ? x1 : (g == 2) ? x2 : x3;
            int gi = g ^ 1;
            float iv = (gi == 0) ? act : (gi == 1) ? x1 : (gi == 2) ? x2 : x3;
            int gz = g ^ 2;
            float zv = (gz == 0) ? act : (gz == 1) ? x1 : (gz == 2) ? x2 : x3;
            int gr = g ^ 3;
            float rv = (gr == 0) ? act : (gr == 1) ? x1 : (gr == 2) ? x2 : x3;

            float cn = fv * cst[r] + iv * rv;
            cst[r] = cn;
            float th = 2.0f / (1.0f + __expf(-2.0f * cn)) - 1.0f;
            float hn = zv * th;
            if (g == 0)
                hT[(mi * 16 + quad * 4 + r) * 16 + nj * 4 + (l15 >> 2)] = f2bf(hn);
        }

        __syncthreads();                       // B2b: hT complete

        // ---- wave0: publish the WG's 1KB CONTIGUOUS patch (blocked layout) ----
        // Two instructions, each 64 lanes x 8B fully contiguous (512B = 8 full
        // lines); single writer per line, no partial-line RMW at the LLC.
        if (wave == 0) {
            const unsigned long long* lp =
                reinterpret_cast<const unsigned long long*>(hT);
            unsigned long long lo = lp[lane], hi = lp[lane + 64];
            size_t base = (size_t)(t + 1) * HSLAB + (size_t)gh * HBLK
                        + (size_t)(gb * 32) * 16;
            __hip_atomic_store((unsigned long long*)&Hall[base + lane * 4],       lo,
                               __ATOMIC_RELAXED, __HIP_MEMORY_SCOPE_AGENT);
            __hip_atomic_store((unsigned long long*)&Hall[base + 256 + lane * 4], hi,
                               __ATOMIC_RELAXED, __HIP_MEMORY_SCOPE_AGENT);
            __builtin_amdgcn_s_waitcnt(0);     // drain this wave's stores
            asm volatile("" ::: "memory");
            if (lane == 0)
                __hip_atomic_store(&Flag[((size_t)(t + 1) * GB + gb) * 64 + gh], 1,
                                   __ATOMIC_RELAXED, __HIP_MEMORY_SCOPE_AGENT);
        }
    }
}

// ---------------------------------------------------------------------------
// y[b][t][o] = Hall[t+1][.][b][.] @ Wob[o][:] + bout[o]   (blocked Hall)
// ---------------------------------------------------------------------------
__global__ void __launch_bounds__(256, 2)
out_gemm(const unsigned short* __restrict__ Hall,
         const unsigned short* __restrict__ Wob,
         const float* __restrict__ bout,
         float* __restrict__ y)
{
    const int tid  = threadIdx.x, wave = tid >> 6, lane = tid & 63;
    const int quad = lane >> 4, l15 = lane & 15;
    const int R    = blockIdx.x * 64 + wave * 16;      // flat row t*128+b

    f32x4 acc[4];
    #pragma unroll
    for (int nt = 0; nt < 4; ++nt) {
        float bb = bout[nt * 16 + l15];
        acc[nt] = {bb, bb, bb, bb};
    }
    const int fr = R + l15;                    // flat row; same t across the wave
    const unsigned short* ap = Hall + ((size_t)(fr >> 7) + 1) * HSLAB
                             + (size_t)(fr & 127) * 16
                             + (quad >> 1) * HBLK + (quad & 1) * 8;
    #pragma unroll 4
    for (int kk = 0; kk < 32; ++kk) {          // k-chunk kk covers blocks 2kk,2kk+1
        bf16x8 av = *reinterpret_cast<const bf16x8*>(ap + (size_t)kk * (2 * HBLK));
        #pragma unroll
        for (int nt = 0; nt < 4; ++nt) {
            bf16x8 bv = *reinterpret_cast<const bf16x8*>(
                Wob + (size_t)(nt * 16 + l15) * H_ + kk * 32 + quad * 8);
            acc[nt] = MFMA(av, bv, acc[nt]);
        }
    }
    #pragma unroll
    for (int nt = 0; nt < 4; ++nt)
        #pragma unroll
        for (int r = 0; r < 4; ++r) {
            int row = R + quad * 4 + r;
            int b = row & 127, t = row >> 7;
            y[((size_t)b << 15) + ((size_t)t << 6) + nt * 16 + l15] = acc[nt][r];
        }
}

// ---------------------------------------------------------------------------
extern "C" void kernel_launch(void* const* d_in, const int* in_sizes, int n_in,
                              void* d_out, int out_size, void* d_ws, size_t ws_size,
                              hipStream_t stream)
{
    const float* u    = (const float*)d_in[0];
    const float* x0   = (const float*)d_in[1];
    const float* kfiz = (const float*)d_in[2];
    const float* bfiz = (const float*)d_in[3];
    const float* kr   = (const float*)d_in[4];
    const float* br   = (const float*)d_in[5];
    const float* wo   = (const float*)d_in[6];
    const float* bo   = (const float*)d_in[7];
    float* y = (float*)d_out;

    char* ws = (char*)d_ws;
    size_t off = 0;
    unsigned short* Wp    = (unsigned short*)(ws + off); off += (size_t)4096 * KTOT * 2;        // 9,437,184
    float*          biasp = (float*)(ws + off);          off += (size_t)4096 * 4;               // 16,384
    unsigned short* Wob   = (unsigned short*)(ws + off); off += (size_t)OUT_ * H_ * 2;          // 131,072
    unsigned short* Ubf   = (unsigned short*)(ws + off); off += (size_t)T_ * B_ * IN_ * 2;      // 16,777,216
    unsigned short* Hall  = (unsigned short*)(ws + off); off += (size_t)(T_ + 1) * B_ * H_ * 2; // 134,479,872
    int*            Flag  = (int*)(ws + off);            off += (size_t)(T_ + 1) * GB * 64 * 4; // 525,312
    if (off > ws_size) return;   // workspace too small: deterministic visible failure

    hipMemsetAsync(Flag, 0, (size_t)(T_ + 1) * GB * 64 * 4, stream);
    hipLaunchKernelGGL(pack_weights, dim3(4096),  dim3(256), 0, stream, kfiz, kr, bfiz, br, Wp, biasp);
    hipLaunchKernelGGL(pack_u,       dim3(32768), dim3(256), 0, stream, u, Ubf);
    hipLaunchKernelGGL(pack_wout,    dim3(64),    dim3(256), 0, stream, wo, Wob);

    void* args[] = { (void*)&x0, (void*)&Wp, (void*)&biasp, (void*)&Ubf, (void*)&Hall, (void*)&Flag };
    hipLaunchCooperativeKernel((void*)lstm_scan, dim3(GB * GH), dim3(512), args, 0, stream);

    hipLaunchKernelGGL(out_gemm, dim3((T_ * B_) / 64), dim3(256), 0, stream, Hall, Wob, bo, y);
}